// Round 9
// baseline (327.632 us; speedup 1.0000x reference)
//
#include <hip/hip_runtime.h>
#include <math.h>

#define TOK_PER_BLK 8
#define THREADS 256
#define NROWS 24
#define PCOL 20        // 16 partials + pad (80B stride: float4-aligned rows)
#define TAU_INV 20.0f  // 1/0.05

typedef _Float16 half2_t __attribute__((ext_vector_type(2)));

// ---------------------------------------------------------------------------
// Stage 0: fold (1+gamma) into the 24 weight rows, f16 pairs, PERMUTED so in
// hc_dots thread tid's two uint4 loads deliver the 16 k-elements matching its
// x quads (k = q*1024 + 4*tid .. +3, q = 0..3). Unchanged from R11/R12.
// ---------------------------------------------------------------------------
__global__ void fold_gamma(const float* __restrict__ w_res,
                           const float* __restrict__ w_pre,
                           const float* __restrict__ w_post,
                           const float* __restrict__ gamma,
                           unsigned int* __restrict__ wf) {
    const int idx = blockIdx.x * THREADS + threadIdx.x;   // 0 .. 24*2048-1
    const int row = idx >> 11;
    const int j   = idx & 2047;
    const int o   = j >> 2;
    const int pp  = j & 3;
    const int t   = o & 255;
    const int quad = pp >> 1;
    int base;
    if (o < 256) base = (quad == 0) ? (4 * t)        : (1024 + 4 * t);
    else         base = (quad == 0) ? (2048 + 4 * t) : (3072 + 4 * t);
    const int k0 = base + 2 * (pp & 1);

    const float* src = (row < 16) ? (w_res + ((size_t)row << 12))
                     : (row < 20) ? (w_pre + ((size_t)(row - 16) << 12))
                                  : (w_post + ((size_t)(row - 20) << 12));
    float v0 = src[k0]     * (1.0f + gamma[k0]);
    float v1 = src[k0 + 1] * (1.0f + gamma[k0 + 1]);
    union { _Float16 h[2]; unsigned int u; } cvt;
    cvt.h[0] = (_Float16)v0;
    cvt.h[1] = (_Float16)v1;
    wf[idx] = cvt.u;
}

// ---------------------------------------------------------------------------
// R13 hc_dots: TOK=8 fat blocks (T-B experiment). R12 isolated dots = 79us of
// the 122us total with HBM 11% / VALU 22% — pure latency. R10 falsified the
// residency theory; this round tests per-block MLP depth: 32 outstanding
// phase-1 loads (was 16), weight traffic halved (1024 x 192KB), per-row
// compute (~350cyc, 64 fdot2) now covers the depth-2 weight prefetch.
// __launch_bounds__(256,1): allocator spills toward 2x declared min-waves
// (R4/R5/R7 evidence); peak live set here ~210 regs needs the 256 budget.
// Tripwire: WRITE_SIZE >> 1 MB means spill returned.
// ---------------------------------------------------------------------------
__global__ __launch_bounds__(THREADS, 1)
void hc_dots(const float* __restrict__ resid,
             const unsigned int* __restrict__ wf,
             float* __restrict__ g_raw)
{
    __shared__ __align__(16) float sh_part[NROWS * TOK_PER_BLK][PCOL]; // 15.4 KB
    __shared__ __align__(16) float sh_ssqp[TOK_PER_BLK][PCOL];         // 0.6 KB

    const int tid  = threadIdx.x;
    const int wave = tid >> 6;
    const int lane = tid & 63;
    const long tok0 = (long)blockIdx.x * TOK_PER_BLK;

    // ---- Phase 1: 32-deep load burst -> fp32 sumsq -> packed f16 regs ----
    const float4* hp = (const float4*)resid + tok0 * 1024;
    float4 pf[TOK_PER_BLK][4];          // transient: dies after conversion
    #pragma unroll
    for (int m = 0; m < TOK_PER_BLK; ++m)
        #pragma unroll
        for (int q = 0; q < 4; ++q)
            pf[m][q] = hp[m * 1024 + q * 256 + tid];

    half2_t xh[TOK_PER_BLK][8];
    #pragma unroll
    for (int m = 0; m < TOK_PER_BLK; ++m) {
        float s = 0.f;
        #pragma unroll
        for (int q = 0; q < 4; ++q) {
            float4 v = pf[m][q];
            s += v.x * v.x + v.y * v.y + v.z * v.z + v.w * v.w;
            xh[m][2 * q]     = half2_t{(_Float16)v.x, (_Float16)v.y};
            xh[m][2 * q + 1] = half2_t{(_Float16)v.z, (_Float16)v.w};
        }
        s += __shfl_xor(s, 4, 64);
        s += __shfl_xor(s, 8, 64);
        s += __shfl_xor(s, 16, 64);
        s += __shfl_xor(s, 32, 64);
        if (lane < 4) sh_ssqp[m][(wave << 2) | lane] = s;
    }

    // ---- Phase 2: 24 rows via fdot2, depth-2 (triple) prefetch ----
    const uint4* wp = (const uint4*)wf;      // 512 uint4 per row

    auto load_row = [&](int e, uint4 (&w)[2]) {
        const uint4* wr = wp + ((size_t)e << 9);
        w[0] = wr[tid];
        w[1] = wr[256 + tid];
    };
#define H2(u) __builtin_bit_cast(half2_t, (u))
    auto comp_row = [&](int e, const uint4 (&W)[2]) {
        #pragma unroll
        for (int m = 0; m < TOK_PER_BLK; ++m) {
            float a = 0.f;
            a = __builtin_amdgcn_fdot2(H2(W[0].x), xh[m][0], a, false);
            a = __builtin_amdgcn_fdot2(H2(W[0].y), xh[m][1], a, false);
            a = __builtin_amdgcn_fdot2(H2(W[0].z), xh[m][2], a, false);
            a = __builtin_amdgcn_fdot2(H2(W[0].w), xh[m][3], a, false);
            a = __builtin_amdgcn_fdot2(H2(W[1].x), xh[m][4], a, false);
            a = __builtin_amdgcn_fdot2(H2(W[1].y), xh[m][5], a, false);
            a = __builtin_amdgcn_fdot2(H2(W[1].z), xh[m][6], a, false);
            a = __builtin_amdgcn_fdot2(H2(W[1].w), xh[m][7], a, false);
            a += __shfl_xor(a, 4, 64);
            a += __shfl_xor(a, 8, 64);
            a += __shfl_xor(a, 16, 64);
            a += __shfl_xor(a, 32, 64);
            if (lane < 4) sh_part[e * TOK_PER_BLK + m][(wave << 2) | lane] = a;
        }
    };
#undef H2

    uint4 wA[2], wB[2], wC[2];
    load_row(0, wA);
    load_row(1, wB);
    #pragma unroll 1
    for (int c = 0; c < 8; ++c) {            // rows 3c, 3c+1, 3c+2
        load_row(3 * c + 2, wC);
        comp_row(3 * c, wA);
        if (3 * c + 3 < NROWS) load_row(3 * c + 3, wA);
        comp_row(3 * c + 1, wB);
        if (3 * c + 4 < NROWS) load_row(3 * c + 4, wB);
        comp_row(3 * c + 2, wC);
    }
    __syncthreads();

    // ---- Reduce (16 partials per row-token) + store raw; block ends ----
    if (tid < NROWS * TOK_PER_BLK) {           // 192 threads: one (row,token)
        const int e = tid >> 3, m = tid & 7;
        const float4* src = (const float4*)&sh_part[e * TOK_PER_BLK + m][0];
        float4 s4 = src[0];
        #pragma unroll
        for (int j = 1; j < 4; ++j) {
            float4 v = src[j];
            s4.x += v.x; s4.y += v.y; s4.z += v.z; s4.w += v.w;
        }
        g_raw[(tok0 + m) * 32 + e] = s4.x + s4.y + s4.z + s4.w;
    } else if (tid < NROWS * TOK_PER_BLK + TOK_PER_BLK) {
        const int m = tid - NROWS * TOK_PER_BLK;
        const float4* src = (const float4*)&sh_ssqp[m][0];
        float4 s4 = src[0];
        #pragma unroll
        for (int j = 1; j < 4; ++j) {
            float4 v = src[j];
            s4.x += v.x; s4.y += v.y; s4.z += v.z; s4.w += v.w;
        }
        g_raw[(tok0 + m) * 32 + 24] = s4.x + s4.y + s4.z + s4.w;
    }
}

// ---------------------------------------------------------------------------
// Kernel B: sinkhorn + gates. 16 lanes per token, 4 tokens/wave in parallel.
// Emits combined M[i][j] = Hres[i][j] + Hpost[i]*Hpre[j].  (unchanged)
// ---------------------------------------------------------------------------
__global__ void hc_sinkhorn(const float* __restrict__ g_raw,
                            const float* __restrict__ beta_res,
                            const float* __restrict__ beta_pre,
                            const float* __restrict__ beta_post,
                            const float* __restrict__ p_alpha_res,
                            const float* __restrict__ p_alpha_pre,
                            const float* __restrict__ p_alpha_post,
                            float* __restrict__ g_M)
{
    const int tid  = threadIdx.x;
    const int wave = tid >> 6;
    const int lane = tid & 63;
    const int grp  = lane >> 4;
    const int idx  = lane & 15;          // (i,j): i = idx>>2, j = idx&3
    const int jj   = idx & 3;
    const long t   = (long)blockIdx.x * 16 + wave * 4 + grp;

    const float* rp = g_raw + t * 32;
    float ss    = rp[24];
    float scale = 64.0f / fmaxf(sqrtf(ss), 1e-12f);

    const float a_res  = p_alpha_res[0];
    const float a_pre  = p_alpha_pre[0];
    const float a_post = p_alpha_post[0];

    float Z = (beta_res[idx] + a_res * scale * rp[idx]) * TAU_INV;
    float u = 0.f, v = 0.f;
    #pragma unroll 1
    for (int it = 0; it < 10; ++it) {
        float tv = Z + v;
        float mx = tv;
        mx = fmaxf(mx, __shfl_xor(mx, 1, 64));
        mx = fmaxf(mx, __shfl_xor(mx, 2, 64));
        float sm = __expf(tv - mx);
        sm += __shfl_xor(sm, 1, 64);
        sm += __shfl_xor(sm, 2, 64);
        u = -(mx + __logf(sm));
        tv = Z + u;
        mx = tv;
        mx = fmaxf(mx, __shfl_xor(mx, 4, 64));
        mx = fmaxf(mx, __shfl_xor(mx, 8, 64));
        sm = __expf(tv - mx);
        sm += __shfl_xor(sm, 4, 64);
        sm += __shfl_xor(sm, 8, 64);
        v = -(mx + __logf(sm));
    }
    float P = __expf(Z + u + v);             // Hres[i][j]

    float lpre = beta_pre[jj] + a_pre * scale * rp[16 + jj];
    float mxp = lpre;
    mxp = fmaxf(mxp, __shfl_xor(mxp, 1, 64));
    mxp = fmaxf(mxp, __shfl_xor(mxp, 2, 64));
    float ep = __expf(lpre - mxp);
    float sp = ep;
    sp += __shfl_xor(sp, 1, 64);
    sp += __shfl_xor(sp, 2, 64);
    float hpre = ep / sp;                    // Hpre[jj]
    float lpost = beta_post[jj] + a_post * scale * rp[20 + jj];
    float hpost = 2.0f / (1.0f + __expf(-lpost));  // Hpost[jj]

    float hpost_i = __shfl(hpost, (lane & 48) | (idx >> 2), 64);
    g_M[t * 16 + idx] = P + hpost_i * hpre;
}

// ---------------------------------------------------------------------------
// Kernel C: streaming apply, barrier-free. M address is block-uniform so the
// compiler emits scalar loads (no LDS, no __syncthreads -> no vmcnt(0) drain
// between the M read and the x loads). fp32 end to end.
// ---------------------------------------------------------------------------
__global__ void hc_apply(const float* __restrict__ resid,
                         const float* __restrict__ g_M,
                         float* __restrict__ out)
{
    const int tid = threadIdx.x;
    const long t  = blockIdx.x;

    const float4* xp = (const float4*)resid + t * 1024;
    float4 x0 = xp[tid], x1 = xp[256 + tid], x2 = xp[512 + tid], x3 = xp[768 + tid];

    const float* Mp = g_M + t * 16;          // block-uniform -> scalar loads
    float Mv[16];
    #pragma unroll
    for (int k = 0; k < 16; ++k) Mv[k] = Mp[k];

    float4* op = (float4*)out + t * 1024;
    #pragma unroll
    for (int i = 0; i < 4; ++i) {
        float4 o;
        o.x = Mv[i*4+0]*x0.x + Mv[i*4+1]*x1.x + Mv[i*4+2]*x2.x + Mv[i*4+3]*x3.x;
        o.y = Mv[i*4+0]*x0.y + Mv[i*4+1]*x1.y + Mv[i*4+2]*x2.y + Mv[i*4+3]*x3.y;
        o.z = Mv[i*4+0]*x0.z + Mv[i*4+1]*x1.z + Mv[i*4+2]*x2.z + Mv[i*4+3]*x3.z;
        o.w = Mv[i*4+0]*x0.w + Mv[i*4+1]*x1.w + Mv[i*4+2]*x2.w + Mv[i*4+3]*x3.w;
        op[i * 256 + tid] = o;
    }
}

extern "C" void kernel_launch(void* const* d_in, const int* in_sizes, int n_in,
                              void* d_out, int out_size, void* d_ws, size_t ws_size,
                              hipStream_t stream) {
    const float* resid      = (const float*)d_in[0];
    const float* gamma      = (const float*)d_in[1];
    const float* w_res      = (const float*)d_in[2];
    const float* w_pre      = (const float*)d_in[3];
    const float* w_post     = (const float*)d_in[4];
    const float* beta_res   = (const float*)d_in[5];
    const float* beta_pre   = (const float*)d_in[6];
    const float* beta_post  = (const float*)d_in[7];
    const float* alpha_res  = (const float*)d_in[8];
    const float* alpha_pre  = (const float*)d_in[9];
    const float* alpha_post = (const float*)d_in[10];
    float* out = (float*)d_out;

    const int ntok = in_sizes[0] / 4096;          // B*T = 8192

    // Workspace: wf 192KB | raw ntok*32*4 = 1MB | M ntok*16*4 = 512KB
    char* ws = (char*)d_ws;
    unsigned int* wf  = (unsigned int*)ws;
    float* g_raw      = (float*)(ws + 192 * 1024);
    float* g_M        = (float*)(ws + 192 * 1024 + (size_t)ntok * 32 * 4);
    (void)ws_size;

    fold_gamma<<<NROWS * 2048 / THREADS, THREADS, 0, stream>>>(
        w_res, w_pre, w_post, gamma, wf);

    hc_dots<<<ntok / TOK_PER_BLK, THREADS, 0, stream>>>(resid, wf, g_raw);

    hc_sinkhorn<<<ntok / 16, THREADS, 0, stream>>>(
        g_raw, beta_res, beta_pre, beta_post,
        alpha_res, alpha_pre, alpha_post, g_M);

    hc_apply<<<ntok, THREADS, 0, stream>>>(resid, g_M, out);
}

// Round 11
// 276.985 us; speedup vs baseline: 1.1829x; 1.1829x over previous
//
#include <hip/hip_runtime.h>
#include <math.h>

#define TOK_PER_BLK 2
#define THREADS 256
#define NROWS 24
#define PCOL 68        // 64 partials + 4 pad
#define TAU_INV 20.0f  // 1/0.05
#define WCOPY 8        // weight replicas (per-XCD L2 affinity via blockIdx&7)
#define WROW_U32 2048  // uint32 per row
#define WCOPY_U32 (NROWS * WROW_U32)

typedef _Float16 half2_t __attribute__((ext_vector_type(2)));
typedef float    f32x4  __attribute__((ext_vector_type(4)));  // native vec for
                                                              // nontemporal b/i

// ---------------------------------------------------------------------------
// Prelude: fold (1+gamma) into the 24 weight rows, f16 pairs, PERMUTED so in
// hc_fused thread tid's two uint4 loads deliver the 16 k-elements matching
// its x quads (k = q*1024 + 4*tid .. +3, q=0..3). R14: write 8 identical
// copies; consecutive blocks (round-robin across XCDs) pick copy blockIdx&7
// -> each XCD's L2 caches its own copy, no cross-block same-line contention.
// ---------------------------------------------------------------------------
__global__ void fold_gamma(const float* __restrict__ w_res,
                           const float* __restrict__ w_pre,
                           const float* __restrict__ w_post,
                           const float* __restrict__ gamma,
                           unsigned int* __restrict__ wf) {
    const int idx = blockIdx.x * THREADS + threadIdx.x;   // 0 .. 24*2048-1
    const int row = idx >> 11;
    const int j   = idx & 2047;
    const int o   = j >> 2;
    const int pp  = j & 3;
    const int t   = o & 255;
    const int quad = pp >> 1;
    int base;
    if (o < 256) base = (quad == 0) ? (4 * t)        : (1024 + 4 * t);
    else         base = (quad == 0) ? (2048 + 4 * t) : (3072 + 4 * t);
    const int k0 = base + 2 * (pp & 1);

    const float* src = (row < 16) ? (w_res + ((size_t)row << 12))
                     : (row < 20) ? (w_pre + ((size_t)(row - 16) << 12))
                                  : (w_post + ((size_t)(row - 20) << 12));
    float v0 = src[k0]     * (1.0f + gamma[k0]);
    float v1 = src[k0 + 1] * (1.0f + gamma[k0 + 1]);
    union { _Float16 h[2]; unsigned int u; } cvt;
    cvt.h[0] = (_Float16)v0;
    cvt.h[1] = (_Float16)v1;
    #pragma unroll
    for (int c = 0; c < WCOPY; ++c)
        wf[(size_t)c * WCOPY_U32 + idx] = cvt.u;
}

// ---------------------------------------------------------------------------
// R14/R15 = R11 fused + three convergent edits targeting weight-load latency:
//   (1) NONTEMPORAL x loads / out stores (via ext_vector f32x4 — the builtin
//       rejects HIP_vector_type): the 256MB streams stop allocating in L2, so
//       the 192KB weight set stays L2-resident (R8-R13 synthesis: weight rows
//       were L3-served at ~500-900cy, beyond depth-2 cover; occupancy (R10)
//       and byte-halving (R9) both failed -> latency-bound).
//   (2) weight prefetch depth 2 -> 4 (quad buffer, ~900-1200cy cover).
//   (3) 8x weight replicas picked by blockIdx&7 (per-XCD L2 affinity).
// ALLOCATOR LAW (R4/5/7/8/13): spills toward 2x declared min-waves and
// refuses deep register bursts regardless of budget; keep (256,2), keep all
// load bursts <= ~8 outstanding. Tripwire: WRITE_SIZE != 131072 KB = spill.
// ---------------------------------------------------------------------------
__global__ __launch_bounds__(THREADS, 2)
void hc_fused(const float* __restrict__ resid,
              const unsigned int* __restrict__ wf,
              const float* __restrict__ beta_res,
              const float* __restrict__ beta_pre,
              const float* __restrict__ beta_post,
              const float* __restrict__ p_alpha_res,
              const float* __restrict__ p_alpha_pre,
              const float* __restrict__ p_alpha_post,
              float* __restrict__ out)
{
    __shared__ __align__(16) float sh_part[NROWS * TOK_PER_BLK][PCOL]; // 13.1 KB
    __shared__ __align__(16) float sh_ssqp[TOK_PER_BLK][PCOL];
    __shared__ float sh_raw[TOK_PER_BLK][NROWS];
    __shared__ float sh_ssq[TOK_PER_BLK];
    __shared__ float sh_M[TOK_PER_BLK][16];

    const int tid  = threadIdx.x;
    const int wave = tid >> 6;
    const int lane = tid & 63;
    const long tok0 = (long)blockIdx.x * TOK_PER_BLK;

    // ---------- Phase 1: nontemporal x -> fp32 sumsq -> packed f16 ----------
    const f32x4* hp = (const f32x4*)resid + tok0 * 1024;
    half2_t xh[TOK_PER_BLK][8];
    #pragma unroll
    for (int m = 0; m < TOK_PER_BLK; ++m) {
        f32x4 pf[4];
        #pragma unroll
        for (int q = 0; q < 4; ++q)
            pf[q] = __builtin_nontemporal_load(&hp[m * 1024 + q * 256 + tid]);
        float s = 0.f;
        #pragma unroll
        for (int q = 0; q < 4; ++q) {
            f32x4 v = pf[q];
            s += v.x * v.x + v.y * v.y + v.z * v.z + v.w * v.w;
            xh[m][2 * q]     = half2_t{(_Float16)v.x, (_Float16)v.y};
            xh[m][2 * q + 1] = half2_t{(_Float16)v.z, (_Float16)v.w};
        }
        s += __shfl_xor(s, 16, 64);
        s += __shfl_xor(s, 32, 64);
        if (lane < 16) sh_ssqp[m][wave * 16 + lane] = s;
    }

    // ---------- Phase 2: 24 dots via fdot2, depth-4 (quad) prefetch ---------
    const uint4* wp = (const uint4*)(wf + (size_t)(blockIdx.x & (WCOPY - 1)) * WCOPY_U32);

    auto load_row = [&](int e, uint4 (&w)[2]) {
        const uint4* wr = wp + ((size_t)e << 9);
        w[0] = wr[tid];
        w[1] = wr[256 + tid];
    };
#define H2(u) __builtin_bit_cast(half2_t, (u))
    auto comp_row = [&](int e, const uint4 (&W)[2]) {
        #pragma unroll
        for (int m = 0; m < TOK_PER_BLK; ++m) {
            float a = 0.f;
            a = __builtin_amdgcn_fdot2(H2(W[0].x), xh[m][0], a, false);
            a = __builtin_amdgcn_fdot2(H2(W[0].y), xh[m][1], a, false);
            a = __builtin_amdgcn_fdot2(H2(W[0].z), xh[m][2], a, false);
            a = __builtin_amdgcn_fdot2(H2(W[0].w), xh[m][3], a, false);
            a = __builtin_amdgcn_fdot2(H2(W[1].x), xh[m][4], a, false);
            a = __builtin_amdgcn_fdot2(H2(W[1].y), xh[m][5], a, false);
            a = __builtin_amdgcn_fdot2(H2(W[1].z), xh[m][6], a, false);
            a = __builtin_amdgcn_fdot2(H2(W[1].w), xh[m][7], a, false);
            a += __shfl_xor(a, 16, 64);
            a += __shfl_xor(a, 32, 64);
            if (lane < 16) sh_part[e * TOK_PER_BLK + m][wave * 16 + lane] = a;
        }
    };
#undef H2

    uint4 wA[2], wB[2], wC[2], wD[2];
    load_row(0, wA);
    load_row(1, wB);
    load_row(2, wC);
    load_row(3, wD);
    #pragma unroll 1
    for (int c = 0; c < 6; ++c) {            // rows 4c .. 4c+3
        comp_row(4 * c + 0, wA);
        if (4 * c + 4 < NROWS) load_row(4 * c + 4, wA);
        comp_row(4 * c + 1, wB);
        if (4 * c + 5 < NROWS) load_row(4 * c + 5, wB);
        comp_row(4 * c + 2, wC);
        if (4 * c + 6 < NROWS) load_row(4 * c + 6, wC);
        comp_row(4 * c + 3, wD);
        if (4 * c + 7 < NROWS) load_row(4 * c + 7, wD);
    }
    __syncthreads();

    // ---------------- Reduce: parallel column sums ----------------
    if (tid < NROWS * TOK_PER_BLK) {           // 48 threads: one (row,token)
        const float4* src = (const float4*)&sh_part[tid][0];
        float4 s4 = src[0];
        #pragma unroll
        for (int j = 1; j < 16; ++j) {
            float4 v = src[j];
            s4.x += v.x; s4.y += v.y; s4.z += v.z; s4.w += v.w;
        }
        sh_raw[tid & (TOK_PER_BLK - 1)][tid >> 1] = s4.x + s4.y + s4.z + s4.w;
    } else if (tid < NROWS * TOK_PER_BLK + TOK_PER_BLK) {
        const int m = tid - NROWS * TOK_PER_BLK;
        const float4* src = (const float4*)&sh_ssqp[m][0];
        float4 s4 = src[0];
        #pragma unroll
        for (int j = 1; j < 16; ++j) {
            float4 v = src[j];
            s4.x += v.x; s4.y += v.y; s4.z += v.z; s4.w += v.w;
        }
        sh_ssq[m] = s4.x + s4.y + s4.z + s4.w;
    }
    __syncthreads();

    // ---------------- Phase 3: sinkhorn + gates (wave m -> token m) ---------
    if (wave < TOK_PER_BLK) {
        const int m   = wave;
        const int idx = lane & 15;     // (i,j): i = idx>>2, j = idx&3
        const int jj  = idx & 3;

        float ss    = sh_ssq[m];
        float scale = 64.0f / fmaxf(sqrtf(ss), 1e-12f);

        const float a_res  = p_alpha_res[0];
        const float a_pre  = p_alpha_pre[0];
        const float a_post = p_alpha_post[0];

        float Z = (beta_res[idx] + a_res * scale * sh_raw[m][idx]) * TAU_INV;
        float u = 0.f, v = 0.f;
        #pragma unroll 1
        for (int it = 0; it < 10; ++it) {
            float tv = Z + v;
            float mx = tv;
            mx = fmaxf(mx, __shfl_xor(mx, 1, 64));
            mx = fmaxf(mx, __shfl_xor(mx, 2, 64));
            float sm = __expf(tv - mx);
            sm += __shfl_xor(sm, 1, 64);
            sm += __shfl_xor(sm, 2, 64);
            u = -(mx + __logf(sm));
            tv = Z + u;
            mx = tv;
            mx = fmaxf(mx, __shfl_xor(mx, 4, 64));
            mx = fmaxf(mx, __shfl_xor(mx, 8, 64));
            sm = __expf(tv - mx);
            sm += __shfl_xor(sm, 4, 64);
            sm += __shfl_xor(sm, 8, 64);
            v = -(mx + __logf(sm));
        }
        float P = __expf(Z + u + v);           // Hres[i][j]

        float lpre = beta_pre[jj] + a_pre * scale * sh_raw[m][16 + jj];
        float mxp = lpre;
        mxp = fmaxf(mxp, __shfl_xor(mxp, 1, 64));
        mxp = fmaxf(mxp, __shfl_xor(mxp, 2, 64));
        float ep = __expf(lpre - mxp);
        float sp = ep;
        sp += __shfl_xor(sp, 1, 64);
        sp += __shfl_xor(sp, 2, 64);
        float hpre = ep / sp;                  // Hpre[jj]
        float lpost = beta_post[jj] + a_post * scale * sh_raw[m][20 + jj];
        float hpost = 2.0f / (1.0f + __expf(-lpost));  // Hpost[jj]

        float hpost_i = __shfl(hpost, idx >> 2, 64);
        float Mv = P + hpost_i * hpre;         // M = Hres + Hpost x Hpre
        if (lane < 16) sh_M[m][idx] = Mv;
    }
    __syncthreads();

    // ---------- Phase 4: out = M . x (f16 x), nontemporal stores ------------
    #pragma unroll
    for (int m = 0; m < TOK_PER_BLK; ++m) {
        float Mv[16];
        #pragma unroll
        for (int k = 0; k < 16; ++k) Mv[k] = sh_M[m][k];

        float xm[16];
        #pragma unroll
        for (int q = 0; q < 4; ++q) {
            xm[4*q + 0] = (float)xh[m][2*q][0];
            xm[4*q + 1] = (float)xh[m][2*q][1];
            xm[4*q + 2] = (float)xh[m][2*q + 1][0];
            xm[4*q + 3] = (float)xh[m][2*q + 1][1];
        }

        f32x4* op = (f32x4*)out + (tok0 + m) * 1024;
        #pragma unroll
        for (int i = 0; i < 4; ++i) {
            f32x4 o;
            o.x = Mv[i*4+0]*xm[0] + Mv[i*4+1]*xm[4]  + Mv[i*4+2]*xm[8]  + Mv[i*4+3]*xm[12];
            o.y = Mv[i*4+0]*xm[1] + Mv[i*4+1]*xm[5]  + Mv[i*4+2]*xm[9]  + Mv[i*4+3]*xm[13];
            o.z = Mv[i*4+0]*xm[2] + Mv[i*4+1]*xm[6]  + Mv[i*4+2]*xm[10] + Mv[i*4+3]*xm[14];
            o.w = Mv[i*4+0]*xm[3] + Mv[i*4+1]*xm[7]  + Mv[i*4+2]*xm[11] + Mv[i*4+3]*xm[15];
            __builtin_nontemporal_store(o, &op[i * 256 + tid]);
        }
    }
}

extern "C" void kernel_launch(void* const* d_in, const int* in_sizes, int n_in,
                              void* d_out, int out_size, void* d_ws, size_t ws_size,
                              hipStream_t stream) {
    const float* resid      = (const float*)d_in[0];
    const float* gamma      = (const float*)d_in[1];
    const float* w_res      = (const float*)d_in[2];
    const float* w_pre      = (const float*)d_in[3];
    const float* w_post     = (const float*)d_in[4];
    const float* beta_res   = (const float*)d_in[5];
    const float* beta_pre   = (const float*)d_in[6];
    const float* beta_post  = (const float*)d_in[7];
    const float* alpha_res  = (const float*)d_in[8];
    const float* alpha_pre  = (const float*)d_in[9];
    const float* alpha_post = (const float*)d_in[10];
    float* out = (float*)d_out;

    unsigned int* wf = (unsigned int*)d_ws;       // 8 copies x 192 KB = 1.5 MB
    (void)ws_size;

    fold_gamma<<<NROWS * 2048 / THREADS, THREADS, 0, stream>>>(
        w_res, w_pre, w_post, gamma, wf);

    const int ntok = in_sizes[0] / 4096;          // B*T = 8192
    const int grid = ntok / TOK_PER_BLK;          // 4096

    hc_fused<<<grid, THREADS, 0, stream>>>(resid, wf, beta_res, beta_pre,
                                           beta_post, alpha_res, alpha_pre,
                                           alpha_post, out);
}